// Round 2
// baseline (100076.019 us; speedup 1.0000x reference)
//
#include <hip/hip_runtime.h>
#include <math.h>

#define T_   1024
#define B_   128
#define H_   512
#define I_   256
#define NWG  192     // 3 gates x 64 col-groups
#define NTH  256
#define NC   8       // columns per workgroup
#define NZR  128     // bar1 arrivers (z+r wgs)
#define NH   64      // bar2 arrivers (h wgs)

// ---------------- barrier helpers (monotonic counters, agent scope) ----------
__device__ __forceinline__ void fence_rel_arrive(int* cnt) {
    __threadfence();            // drain my loads/stores to device-coherent point
    __syncthreads();            // all threads' fences done before leader arrives
    if (threadIdx.x == 0)
        __hip_atomic_fetch_add(cnt, 1, __ATOMIC_RELAXED, __HIP_MEMORY_SCOPE_AGENT);
}

__device__ __forceinline__ void wait_ge_acq(int* cnt, int target) {
    if (threadIdx.x == 0) {
        while (__hip_atomic_load(cnt, __ATOMIC_RELAXED, __HIP_MEMORY_SCOPE_AGENT) < target)
            __builtin_amdgcn_s_sleep(2);
    }
    __syncthreads();
    __threadfence();            // acquire: invalidate stale cached lines
}

// ---- acc[c] += sum_k Arow[k] * W[k][c], W rows stride H_, kn multiple of 4 ----
__device__ __forceinline__ void accum_run(const float* __restrict__ Arow,
                                          const float* __restrict__ Wp,
                                          int kn, float acc[NC]) {
    Wp = (const float*)__builtin_assume_aligned(Wp, 32);
    #pragma unroll 2
    for (int k = 0; k < kn; k += 4) {
        float4 a = *(const float4*)(Arow + k);
        const float* w0 = Wp + (size_t)k * H_;
        #pragma unroll
        for (int kk = 0; kk < 4; ++kk) {
            float av = (&a.x)[kk];
            const float* wr = w0 + (size_t)kk * H_;
            #pragma unroll
            for (int c = 0; c < NC; ++c)
                acc[c] = fmaf(av, wr[c], acc[c]);
        }
    }
}

// combine k-halves: kh==1 threads dump into LDS, kh==0 threads add
__device__ __forceinline__ void kh_combine(float acc[NC], float (*red)[NC], int r, int kh) {
    __syncthreads();   // protect previous use of red
    if (kh) {
        float4* p = (float4*)&red[r][0];
        p[0] = make_float4(acc[0], acc[1], acc[2], acc[3]);
        p[1] = make_float4(acc[4], acc[5], acc[6], acc[7]);
    }
    __syncthreads();
    if (!kh) {
        #pragma unroll
        for (int c = 0; c < NC; ++c) acc[c] += red[r][c];
    }
}

__device__ __forceinline__ float sigmoidf_(float x) { return 1.0f / (1.0f + expf(-x)); }

__global__ __launch_bounds__(NTH, 1) void scagru_persist(
    const float* __restrict__ input, const float* __restrict__ state,
    const float* __restrict__ W_zh, const float* __restrict__ W_zx, const float* __restrict__ b_z,
    const float* __restrict__ W_rh, const float* __restrict__ W_rx, const float* __restrict__ b_r,
    const float* __restrict__ W_hh, const float* __restrict__ W_hx, const float* __restrict__ b_h,
    const float* __restrict__ W_ch, const float* __restrict__ b_c,
    float* __restrict__ out,
    float* __restrict__ h_buf, float* __restrict__ hr_buf, float* __restrict__ z_buf,
    int* __restrict__ bar)
{
    const int w    = blockIdx.x;
    const int gate = w >> 6;          // 0:z 1:r 2:h
    const int cg   = w & 63;
    const int col0 = cg * NC;
    const int tid  = threadIdx.x;
    const int r    = tid & 127;       // batch row
    const int kh   = tid >> 7;        // k-half (0/1)

    __shared__ float red[B_][NC];

    const float* Wh = (gate == 0) ? W_zh : (gate == 1) ? W_rh : W_hh;
    const float* Wx = (gate == 0) ? W_zx : (gate == 1) ? W_rx : W_hx;
    const float* bg = (gate == 0) ? b_z  : (gate == 1) ? b_r  : b_h;

    int* cnt1 = bar;        // z/r arrive after phase A; h waits
    int* cnt2 = bar + 32;   // h arrives after phase B; z/r wait (separate line)

    // -------- prologue: context slice c[:, col0..col0+8) + fold gate bias ----
    float cctx[NC];
    {
        float acc[NC];
        #pragma unroll
        for (int c = 0; c < NC; ++c) acc[c] = 0.f;
        accum_run(state + (size_t)r * H_ + kh * 256,
                  W_ch + (size_t)(kh * 256) * H_ + col0, 256, acc);
        kh_combine(acc, red, r, kh);
        if (!kh) {
            #pragma unroll
            for (int c = 0; c < NC; ++c)
                cctx[c] = fmaxf(acc[c] + b_c[col0 + c], 0.f) + bg[col0 + c];
        }
    }

    // h-wgs: initialize h_buf slice from state, publish
    if (gate == 2) {
        if (!kh) {
            float4 s0 = *(const float4*)(state + (size_t)r * H_ + col0);
            float4 s1 = *(const float4*)(state + (size_t)r * H_ + col0 + 4);
            *(float4*)(h_buf + (size_t)r * H_ + col0)     = s0;
            *(float4*)(h_buf + (size_t)r * H_ + col0 + 4) = s1;
        }
        fence_rel_arrive(cnt2);
    }

    // x-projection prefetch for t=0
    float accx[NC];
    #pragma unroll
    for (int c = 0; c < NC; ++c) accx[c] = 0.f;
    accum_run(input + (size_t)r * I_ + kh * 128,
              Wx + (size_t)(kh * 128) * H_ + col0, 128, accx);

    for (int t = 0; t < T_; ++t) {
        if (gate < 2) {
            // ---------------- phase A: z / r ----------------
            wait_ge_acq(cnt2, NH * (t + 1));
            float acc[NC];
            #pragma unroll
            for (int c = 0; c < NC; ++c) acc[c] = accx[c];
            accum_run(h_buf + (size_t)r * H_ + kh * 256,
                      Wh + (size_t)(kh * 256) * H_ + col0, 256, acc);
            kh_combine(acc, red, r, kh);
            if (!kh) {
                float v[NC];
                if (gate == 0) {
                    #pragma unroll
                    for (int c = 0; c < NC; ++c) v[c] = sigmoidf_(acc[c] + cctx[c]);
                    *(float4*)(z_buf + (size_t)r * H_ + col0)     = make_float4(v[0], v[1], v[2], v[3]);
                    *(float4*)(z_buf + (size_t)r * H_ + col0 + 4) = make_float4(v[4], v[5], v[6], v[7]);
                } else {
                    float4 h0 = *(const float4*)(h_buf + (size_t)r * H_ + col0);
                    float4 h1 = *(const float4*)(h_buf + (size_t)r * H_ + col0 + 4);
                    #pragma unroll
                    for (int c = 0; c < NC; ++c) v[c] = sigmoidf_(acc[c] + cctx[c]);
                    *(float4*)(hr_buf + (size_t)r * H_ + col0) =
                        make_float4(v[0]*h0.x, v[1]*h0.y, v[2]*h0.z, v[3]*h0.w);
                    *(float4*)(hr_buf + (size_t)r * H_ + col0 + 4) =
                        make_float4(v[4]*h1.x, v[5]*h1.y, v[6]*h1.z, v[7]*h1.w);
                }
            }
            fence_rel_arrive(cnt1);
            if (t + 1 < T_) {
                #pragma unroll
                for (int c = 0; c < NC; ++c) accx[c] = 0.f;
                accum_run(input + (size_t)(t + 1) * B_ * I_ + (size_t)r * I_ + kh * 128,
                          Wx + (size_t)(kh * 128) * H_ + col0, 128, accx);
            }
        } else {
            // ---------------- phase B: h-candidate + update ----------------
            wait_ge_acq(cnt1, NZR * (t + 1));
            float acc[NC];
            #pragma unroll
            for (int c = 0; c < NC; ++c) acc[c] = accx[c];
            accum_run(hr_buf + (size_t)r * H_ + kh * 256,
                      Wh + (size_t)(kh * 256) * H_ + col0, 256, acc);
            kh_combine(acc, red, r, kh);
            if (!kh) {
                float4 z0 = *(const float4*)(z_buf + (size_t)r * H_ + col0);
                float4 z1 = *(const float4*)(z_buf + (size_t)r * H_ + col0 + 4);
                float4 h0 = *(const float4*)(h_buf + (size_t)r * H_ + col0);
                float4 h1 = *(const float4*)(h_buf + (size_t)r * H_ + col0 + 4);
                float zz[NC] = {z0.x, z0.y, z0.z, z0.w, z1.x, z1.y, z1.z, z1.w};
                float hh[NC] = {h0.x, h0.y, h0.z, h0.w, h1.x, h1.y, h1.z, h1.w};
                float hn[NC];
                #pragma unroll
                for (int c = 0; c < NC; ++c) {
                    float hc = tanhf(acc[c] + cctx[c]);
                    hn[c] = (1.f - zz[c]) * hh[c] + zz[c] * hc;
                }
                *(float4*)(h_buf + (size_t)r * H_ + col0)     = make_float4(hn[0], hn[1], hn[2], hn[3]);
                *(float4*)(h_buf + (size_t)r * H_ + col0 + 4) = make_float4(hn[4], hn[5], hn[6], hn[7]);
                if (t == T_ - 1) {
                    *(float4*)(out + (size_t)r * H_ + col0)     = make_float4(hn[0], hn[1], hn[2], hn[3]);
                    *(float4*)(out + (size_t)r * H_ + col0 + 4) = make_float4(hn[4], hn[5], hn[6], hn[7]);
                }
            }
            fence_rel_arrive(cnt2);
            if (t + 1 < T_) {
                #pragma unroll
                for (int c = 0; c < NC; ++c) accx[c] = 0.f;
                accum_run(input + (size_t)(t + 1) * B_ * I_ + (size_t)r * I_ + kh * 128,
                          Wx + (size_t)(kh * 128) * H_ + col0, 128, accx);
            }
        }
    }
}

extern "C" void kernel_launch(void* const* d_in, const int* in_sizes, int n_in,
                              void* d_out, int out_size, void* d_ws, size_t ws_size,
                              hipStream_t stream)
{
    const float* input = (const float*)d_in[0];
    const float* state = (const float*)d_in[1];
    const float* W_zh  = (const float*)d_in[2];
    const float* W_zx  = (const float*)d_in[3];
    const float* b_z   = (const float*)d_in[4];
    const float* W_rh  = (const float*)d_in[5];
    const float* W_rx  = (const float*)d_in[6];
    const float* b_r   = (const float*)d_in[7];
    const float* W_hh  = (const float*)d_in[8];
    const float* W_hx  = (const float*)d_in[9];
    const float* b_h   = (const float*)d_in[10];
    const float* W_ch  = (const float*)d_in[11];
    const float* b_c   = (const float*)d_in[12];

    float* out = (float*)d_out;
    float* ws  = (float*)d_ws;

    const size_t BH = (size_t)B_ * H_;           // 65536
    float* h_buf  = ws;
    float* hr_buf = ws + BH;
    float* z_buf  = ws + 2 * BH;
    int*   bar    = (int*)((char*)d_ws + 3 * BH * sizeof(float));

    hipMemsetAsync(bar, 0, 256, stream);

    scagru_persist<<<dim3(NWG), dim3(NTH), 0, stream>>>(
        input, state,
        W_zh, W_zx, b_z, W_rh, W_rx, b_r, W_hh, W_hx, b_h, W_ch, b_c,
        out, h_buf, hr_buf, z_buf, bar);
}

// Round 3
// 62468.811 us; speedup vs baseline: 1.6020x; 1.6020x over previous
//
#include <hip/hip_runtime.h>
#include <math.h>

#define T_   1024
#define B_   128
#define H_   512
#define I_   256
#define NWG  192     // 3 gates x 64 col-groups
#define NTH  256
#define NC   8       // columns per workgroup
#define NZR  128     // bar1 arrivers (z+r wgs)
#define NH   64      // bar2 arrivers (h wgs)

// ---- coherent (cross-XCD) access helpers: per-access sc0/sc1, NO cache-wide fences ----
__device__ __forceinline__ float co_ld(const float* p) {
    return __hip_atomic_load(p, __ATOMIC_RELAXED, __HIP_MEMORY_SCOPE_AGENT);
}
__device__ __forceinline__ void co_st(float* p, float v) {
    __hip_atomic_store(p, v, __ATOMIC_RELAXED, __HIP_MEMORY_SCOPE_AGENT);
}

// arrive: __syncthreads() drains each thread's vmcnt (stores complete at coherence
// point, since they are sc1 write-through); leader then does a RELEASE add (its
// buffer_wbl2 is cheap: L2 holds no dirty lines in this kernel).
__device__ __forceinline__ void arrive_release(int* cnt) {
    __syncthreads();
    if (threadIdx.x == 0)
        __hip_atomic_fetch_add(cnt, 1, __ATOMIC_RELEASE, __HIP_MEMORY_SCOPE_AGENT);
}

// wait: relaxed poll (no acquire — subsequent data reads are per-access coherent).
// __syncthreads() after the poll is also the compiler barrier that stops hoisting.
__device__ __forceinline__ void wait_flag(int* cnt, int target) {
    if (threadIdx.x == 0) {
        while (__hip_atomic_load(cnt, __ATOMIC_RELAXED, __HIP_MEMORY_SCOPE_AGENT) < target)
            __builtin_amdgcn_s_sleep(1);
    }
    __syncthreads();
}

// prologue-only: acc[c] += sum_k Arow[k] * W[k][col0+c]  (normal cached loads)
__device__ __forceinline__ void accum_global(const float* __restrict__ Arow,
                                             const float* __restrict__ Wp,
                                             int kn, float acc[NC]) {
    #pragma unroll 2
    for (int k = 0; k < kn; k += 4) {
        float4 a = *(const float4*)(Arow + k);
        const float* w0 = Wp + (size_t)k * H_;
        #pragma unroll
        for (int kk = 0; kk < 4; ++kk) {
            float av = (&a.x)[kk];
            const float* wr = w0 + (size_t)kk * H_;
            #pragma unroll
            for (int c = 0; c < NC; ++c) acc[c] = fmaf(av, wr[c], acc[c]);
        }
    }
}

// steady-state h-side GEMM: A from transposed coherent buffer, W from LDS
__device__ __forceinline__ void accum_coh(const float* __restrict__ AT,  // + (kh*256)*B_ + r
                                          const float* __restrict__ wlds, // + (kh*256)*NC
                                          float acc[NC]) {
    #pragma unroll 4
    for (int k = 0; k < 256; ++k) {
        float av = co_ld(AT + (size_t)k * B_);
        const float* wr = wlds + k * NC;
        #pragma unroll
        for (int c = 0; c < NC; ++c) acc[c] = fmaf(av, wr[c], acc[c]);
    }
}

// x-projection: input row (normal cached float4) x LDS weights
__device__ __forceinline__ void accum_x(const float* __restrict__ xrow,   // + kh*128
                                        const float* __restrict__ wlds,   // + (kh*128)*NC
                                        float acc[NC]) {
    #pragma unroll 2
    for (int k = 0; k < 128; k += 4) {
        float4 a = *(const float4*)(xrow + k);
        #pragma unroll
        for (int kk = 0; kk < 4; ++kk) {
            float av = (&a.x)[kk];
            const float* wr = wlds + (k + kk) * NC;
            #pragma unroll
            for (int c = 0; c < NC; ++c) acc[c] = fmaf(av, wr[c], acc[c]);
        }
    }
}

__device__ __forceinline__ void kh_combine(float acc[NC], float (*red)[NC], int r, int kh) {
    __syncthreads();
    if (kh) {
        float4* p = (float4*)&red[r][0];
        p[0] = make_float4(acc[0], acc[1], acc[2], acc[3]);
        p[1] = make_float4(acc[4], acc[5], acc[6], acc[7]);
    }
    __syncthreads();
    if (!kh) {
        #pragma unroll
        for (int c = 0; c < NC; ++c) acc[c] += red[r][c];
    }
}

__device__ __forceinline__ float sigmoidf_(float x) { return 1.0f / (1.0f + expf(-x)); }

__global__ __launch_bounds__(NTH, 1) void scagru_persist(
    const float* __restrict__ input, const float* __restrict__ state,
    const float* __restrict__ W_zh, const float* __restrict__ W_zx, const float* __restrict__ b_z,
    const float* __restrict__ W_rh, const float* __restrict__ W_rx, const float* __restrict__ b_r,
    const float* __restrict__ W_hh, const float* __restrict__ W_hx, const float* __restrict__ b_h,
    const float* __restrict__ W_ch, const float* __restrict__ b_c,
    float* __restrict__ out,
    float* __restrict__ hT, float* __restrict__ hrT, float* __restrict__ zT,
    int* __restrict__ bar)
{
    const int w    = blockIdx.x;
    const int gate = w >> 6;          // 0:z 1:r 2:h
    const int cg   = w & 63;
    const int col0 = cg * NC;
    const int tid  = threadIdx.x;
    const int r    = tid & 127;       // batch row
    const int kh   = tid >> 7;        // k-half (0/1)

    __shared__ float wh_lds[H_ * NC];   // 16 KB: W*h slice [512][8]
    __shared__ float wx_lds[I_ * NC];   // 8 KB:  W*x slice [256][8]
    __shared__ float red[B_][NC];       // 4 KB

    const float* Wh = (gate == 0) ? W_zh : (gate == 1) ? W_rh : W_hh;
    const float* Wx = (gate == 0) ? W_zx : (gate == 1) ? W_rx : W_hx;
    const float* bg = (gate == 0) ? b_z  : (gate == 1) ? b_r  : b_h;

    int* cnt1 = bar;        // z/r arrive after phase A
    int* cnt2 = bar + 32;   // h arrives after phase B (separate cache line)

    // ---- stage weight slices into LDS (one time; normal cached loads) ----
    for (int i = tid; i < H_ * NC; i += NTH)
        wh_lds[i] = Wh[(size_t)(i >> 3) * H_ + col0 + (i & 7)];
    for (int i = tid; i < I_ * NC; i += NTH)
        wx_lds[i] = Wx[(size_t)(i >> 3) * H_ + col0 + (i & 7)];

    // ---- context slice + fold gate bias (normal loads; W_ch streamed once) ----
    float cctx[NC];
    {
        float acc[NC];
        #pragma unroll
        for (int c = 0; c < NC; ++c) acc[c] = 0.f;
        accum_global(state + (size_t)r * H_ + kh * 256,
                     W_ch + (size_t)(kh * 256) * H_ + col0, 256, acc);
        kh_combine(acc, red, r, kh);
        if (!kh) {
            #pragma unroll
            for (int c = 0; c < NC; ++c)
                cctx[c] = fmaxf(acc[c] + b_c[col0 + c], 0.f) + bg[col0 + c];
        }
    }

    // ---- h-wgs publish initial h (transposed, coherent) ----
    if (gate == 2) {
        if (!kh) {
            #pragma unroll
            for (int c = 0; c < NC; ++c)
                co_st(hT + (size_t)(col0 + c) * B_ + r, state[(size_t)r * H_ + col0 + c]);
        }
        arrive_release(cnt2);
    }

    // ---- x-projection prefetch for t=0 ----
    float accx[NC];
    #pragma unroll
    for (int c = 0; c < NC; ++c) accx[c] = 0.f;
    accum_x(input + (size_t)r * I_ + kh * 128, wx_lds + (size_t)(kh * 128) * NC, accx);

    for (int t = 0; t < T_; ++t) {
        if (gate < 2) {
            // ---------------- phase A: z / r ----------------
            wait_flag(cnt2, NH * (t + 1));
            float acc[NC];
            #pragma unroll
            for (int c = 0; c < NC; ++c) acc[c] = accx[c];
            accum_coh(hT + (size_t)(kh * 256) * B_ + r,
                      wh_lds + (size_t)(kh * 256) * NC, acc);
            kh_combine(acc, red, r, kh);
            if (!kh) {
                if (gate == 0) {
                    #pragma unroll
                    for (int c = 0; c < NC; ++c)
                        co_st(zT + (size_t)(col0 + c) * B_ + r, sigmoidf_(acc[c] + cctx[c]));
                } else {
                    #pragma unroll
                    for (int c = 0; c < NC; ++c) {
                        float hv = co_ld(hT + (size_t)(col0 + c) * B_ + r);
                        co_st(hrT + (size_t)(col0 + c) * B_ + r,
                              sigmoidf_(acc[c] + cctx[c]) * hv);
                    }
                }
            }
            arrive_release(cnt1);
            if (t + 1 < T_) {
                #pragma unroll
                for (int c = 0; c < NC; ++c) accx[c] = 0.f;
                accum_x(input + (size_t)(t + 1) * B_ * I_ + (size_t)r * I_ + kh * 128,
                        wx_lds + (size_t)(kh * 128) * NC, accx);
            }
        } else {
            // ---------------- phase B: h-candidate + update ----------------
            wait_flag(cnt1, NZR * (t + 1));
            float acc[NC];
            #pragma unroll
            for (int c = 0; c < NC; ++c) acc[c] = accx[c];
            accum_coh(hrT + (size_t)(kh * 256) * B_ + r,
                      wh_lds + (size_t)(kh * 256) * NC, acc);
            kh_combine(acc, red, r, kh);
            if (!kh) {
                #pragma unroll
                for (int c = 0; c < NC; ++c) {
                    float zz = co_ld(zT + (size_t)(col0 + c) * B_ + r);
                    float hh = co_ld(hT + (size_t)(col0 + c) * B_ + r);
                    float hc = tanhf(acc[c] + cctx[c]);
                    float hn = (1.f - zz) * hh + zz * hc;
                    co_st(hT + (size_t)(col0 + c) * B_ + r, hn);
                    if (t == T_ - 1) out[(size_t)r * H_ + col0 + c] = hn;
                }
            }
            arrive_release(cnt2);
            if (t + 1 < T_) {
                #pragma unroll
                for (int c = 0; c < NC; ++c) accx[c] = 0.f;
                accum_x(input + (size_t)(t + 1) * B_ * I_ + (size_t)r * I_ + kh * 128,
                        wx_lds + (size_t)(kh * 128) * NC, accx);
            }
        }
    }
}

extern "C" void kernel_launch(void* const* d_in, const int* in_sizes, int n_in,
                              void* d_out, int out_size, void* d_ws, size_t ws_size,
                              hipStream_t stream)
{
    const float* input = (const float*)d_in[0];
    const float* state = (const float*)d_in[1];
    const float* W_zh  = (const float*)d_in[2];
    const float* W_zx  = (const float*)d_in[3];
    const float* b_z   = (const float*)d_in[4];
    const float* W_rh  = (const float*)d_in[5];
    const float* W_rx  = (const float*)d_in[6];
    const float* b_r   = (const float*)d_in[7];
    const float* W_hh  = (const float*)d_in[8];
    const float* W_hx  = (const float*)d_in[9];
    const float* b_h   = (const float*)d_in[10];
    const float* W_ch  = (const float*)d_in[11];
    const float* b_c   = (const float*)d_in[12];

    float* out = (float*)d_out;
    float* ws  = (float*)d_ws;

    const size_t HB = (size_t)H_ * B_;           // 65536
    float* hT  = ws;
    float* hrT = ws + HB;
    float* zT  = ws + 2 * HB;
    int*   bar = (int*)((char*)d_ws + 3 * HB * sizeof(float));

    hipMemsetAsync(bar, 0, 256, stream);

    scagru_persist<<<dim3(NWG), dim3(NTH), 0, stream>>>(
        input, state,
        W_zh, W_zx, b_z, W_rh, W_rx, b_r, W_hh, W_hx, b_h, W_ch, b_c,
        out, hT, hrT, zT, bar);
}